// Round 7
// baseline (122.960 us; speedup 1.0000x reference)
//
#include <hip/hip_runtime.h>
#include <hip/hip_bf16.h>

// Problem constants
#define BATCH  16384
#define GATES  1023
#define NPAD   1024
#define OUTF   128

typedef unsigned short ushortT;
typedef short bf16x8 __attribute__((ext_vector_type(8)));
typedef float f32x4 __attribute__((ext_vector_type(4)));

__device__ inline float bf2f(ushortT u) {
    union { unsigned int i; float f; } v;
    v.i = ((unsigned int)u) << 16;
    return v.f;
}
__device__ inline ushortT f2bf(float f) {
    union { float f; unsigned int i; } v;
    v.f = f;
    unsigned int x = v.i;
    unsigned int r = (x + 0x7FFFu + ((x >> 16) & 1u)) >> 16;  // RNE
    return (ushortT)r;
}
// packed f32 pair -> bf16 pair (RNE); compiler lowers to v_cvt_pk_bf16_f32.
__device__ inline unsigned pkbf(float lo, float hi) {
    __hip_bfloat162 h = __float22bfloat162_rn(float2{lo, hi});
    union { __hip_bfloat162 h; unsigned u; } c;
    c.h = h;
    return c.u;
}
// Row-XOR on ushort-index bits 3..5. Spreads multi-row accesses (P1 epilogue
// quads, P3 A-reads). Row-uniform P2 is conflict-free by layout: gate g at
// slot (g+1)^x8 -> deep-tree reads are stride-16B vector reads; slot x8
// (image of 0) is the hole absorbing pad col 1023. [R3-measured: 262K]
__device__ inline int swz8(int row) { return (((row ^ (row >> 3)) & 7) << 3); }

// async global->LDS, 16B/lane; lds base wave-uniform, HW writes base + lane*16.
__device__ inline void gl2lds16(const void* gptr, void* ldsptr) {
    __builtin_amdgcn_global_load_lds(
        (const __attribute__((address_space(1))) void*)gptr,
        (__attribute__((address_space(3))) void*)ldsptr, 16, 0, 0);
}

// Counted-vmcnt raw-barrier discipline (T4 / m201 pattern)
#define WAITV(N) asm volatile("s_waitcnt vmcnt(" #N ")" ::: "memory")
#define WAITL0() asm volatile("s_waitcnt lgkmcnt(0)" ::: "memory")
#define CFENCE() asm volatile("" ::: "memory")
#define HWBAR()  __builtin_amdgcn_s_barrier()
#define SB()     __builtin_amdgcn_sched_barrier(0)

struct RunTag  { static constexpr bool last = false; };
struct LastTag { static constexpr bool last = true;  };

// ---------------- prep: gwT (tiled transpose+pad), zh, gbp ----------------
__global__ __launch_bounds__(256) void k_prep(const float* __restrict__ gw,
                                              const float* __restrict__ gb,
                                              const float* __restrict__ z,
                                              ushortT* __restrict__ gwT,
                                              float* __restrict__ gbp,
                                              ushortT* __restrict__ zh) {
    const int b = blockIdx.x, t = threadIdx.x;
    if (b < 64) {
        __shared__ ushortT tile[64][65];  // pad 65: transposed reads conflict-free
        const int k0 = (b >> 4) * 64, n0 = (b & 15) * 64;
        const int tr = t >> 6, tc = t & 63;
#pragma unroll
        for (int p = 0; p < 16; ++p) {
            int k = p * 4 + tr;
            int n = n0 + tc;
            float v = (n < GATES) ? gw[(size_t)(k0 + k) * GATES + n] : 0.f;
            tile[k][tc] = f2bf(v);
        }
        __syncthreads();
#pragma unroll
        for (int p = 0; p < 2; ++p) {
            int nn = (t >> 3) + p * 32;
            int ks = (t & 7) * 8;
            ushortT o[8];
#pragma unroll
            for (int u = 0; u < 8; ++u) o[u] = tile[ks + u][nn];
            *(bf16x8*)(gwT + (size_t)(n0 + nn) * 256 + k0 + ks) = *(bf16x8*)o;
        }
    } else if (b < 128) {
        int i = (b - 64) * 256 + t;
        const float4* p = (const float4*)z + (size_t)i * 2;
        float4 a = p[0], c = p[1];
        union { unsigned u[4]; bf16x8 v; } o;
        o.u[0] = pkbf(a.x, a.y); o.u[1] = pkbf(a.z, a.w);
        o.u[2] = pkbf(c.x, c.y); o.u[3] = pkbf(c.z, c.w);
        *(bf16x8*)(zh + (size_t)i * 8) = o.v;
    } else {
#pragma unroll
        for (int u = 0; u < 4; ++u) {
            int id = t * 4 + u;
            gbp[id] = (id < GATES) ? gb[id] : 0.f;
        }
    }
}

// ---------------- mega: one block = 64 rows, 512 threads (8 waves) ----------
// Traffic-halving restructure vs R6:
//  * 256 blocks x 64 rows: each block stages gwT+zh once -> L2 staging traffic
//    halves (393 -> 197 MB).
//  * wave M-tile = 32 rows (af[2][8], wave grid 2M x 4N): each B-fragment
//    ds_read feeds 2 MFMAs -> B-side LDS read traffic halves.
//  * LDS: sG 64x1024 bf16 = 128 KB (gates->leaves, R3 layout) + sS 2x16 KB
//    double-buffered staging = 160 KB exactly -> 1 block/CU, 8 waves (2/SIMD).
//  * Phases 16 KB (128n x 64k): 32 in P1, 16 in P3; counted-vmcnt raw barriers
//    (steady WAITV(2), peeled tails WAITV(0)); P3 z-phases 0,1 staged before
//    P2 (T14).
__global__ __launch_bounds__(512) void k_mega(const float* __restrict__ x,
                                              const ushortT* __restrict__ gwT,
                                              const float* __restrict__ gbp,
                                              const ushortT* __restrict__ zh,
                                              float* __restrict__ out) {
    __shared__ __align__(16) ushortT sG[64 * 1024];  // 128 KB
    __shared__ __align__(16) ushortT sS[2][8192];    // 2 x 16 KB

    const int tid = threadIdx.x;
    const int wave = tid >> 6, lane = tid & 63;
    const int quad = lane >> 4, l15 = lane & 15;
    const int wr = wave >> 2, wc = wave & 3;   // 2M x 4N; wave tile 32 x 32
    const int bm = blockIdx.x * 64;
    const int srow = lane >> 2;                // staging row within 16-row group
    const int scol = (lane & 3) * 8;           // staging elem col within 32

    // per-lane staging source bases
    const ushortT* gS = gwT + (size_t)srow * 256 + scol;
    const ushortT* zS = zh + (size_t)srow * 1024 + scol;

    // phase p (0..31): gates n0=(p>>2)*128, k-quarter k0=(p&3)*64; 16 KB
    auto stage_p1 = [&](int p, int buf) {
        int n0 = (p >> 2) << 7, k0 = (p & 3) << 6;
#pragma unroll
        for (int r = 0; r < 2; ++r) {
            int q = wave * 2 + r, kc = q >> 3, e = q & 7;
            gl2lds16(gS + (size_t)(n0 + e * 16) * 256 + k0 + kc * 32,
                     (void*)&sS[buf][kc * 4096 + e * 512]);
        }
    };
    // z-phase zp (0..15): all 128 z-rows, k = zp*64 .. +64; 16 KB
    auto stage_p3 = [&](int zp, int buf) {
#pragma unroll
        for (int r = 0; r < 2; ++r) {
            int q = wave * 2 + r, kc = q >> 3, e = q & 7;
            gl2lds16(zS + (size_t)(e * 16) * 1024 + zp * 64 + kc * 32,
                     (void*)&sS[buf][kc * 4096 + e * 512]);
        }
    };

    // ---- preload A: x rows (f32) -> bf16 frags; af[h][c]: row wr*32+h*16+l15,
    // k = c*32 + quad*8
    bf16x8 af[2][8];
#pragma unroll
    for (int h = 0; h < 2; ++h) {
        const float* xr = x + (size_t)(bm + wr * 32 + h * 16 + l15) * 256;
#pragma unroll
        for (int c = 0; c < 8; ++c) {
            const float4* p = (const float4*)(xr + c * 32 + quad * 8);
            float4 a = p[0], b = p[1];
            union { unsigned u[4]; bf16x8 v; } o;
            o.u[0] = pkbf(a.x, a.y); o.u[1] = pkbf(a.z, a.w);
            o.u[2] = pkbf(b.x, b.y); o.u[3] = pkbf(b.z, b.w);
            af[h][c] = o.v;
        }
    }

    // epilogue row constants (C/D: col=l15, row=quad*4+reg), two 16-row sets
    int eb[2][4], ex[2][4];
#pragma unroll
    for (int h = 0; h < 2; ++h)
#pragma unroll
        for (int r = 0; r < 4; ++r) {
            int row = wr * 32 + h * 16 + quad * 4 + r;
            eb[h][r] = row << 10;
            ex[h][r] = swz8(row);
        }

    // ---- P1 prologue: stage phases 0,1 (newest vmem ops -> fence first)
    CFENCE();
    stage_p1(0, 0);
    stage_p1(1, 1);

    // ---- P1: 8 groups (128 gates) x 4 k-quarter phases; counted pipe ----
    auto p1_group = [&](int g, auto tag) {
        constexpr bool L = decltype(tag)::last;
        f32x4 acc[2][2] = {};
        float bs[2];
#pragma unroll
        for (int kq = 0; kq < 4; ++kq) {
            if (L && kq == 3) { WAITV(0); } else { WAITV(2); }
            HWBAR(); CFENCE(); SB();
            if (kq == 0) {   // bias: consumed at kq==3, ~3 phases away
                bs[0] = gbp[g * 128 + wc * 32 + l15];
                bs[1] = gbp[g * 128 + wc * 32 + 16 + l15];
            }
            const int buf = kq & 1;
#pragma unroll
            for (int s = 0; s < 2; ++s) {
                bf16x8 b0[2];
#pragma unroll
                for (int j = 0; j < 2; ++j)
                    b0[j] = *(const bf16x8*)(&sS[buf][s * 4096 +
                                                      (wc * 32 + j * 16 + l15) * 32 +
                                                      quad * 8]);
                __builtin_amdgcn_s_setprio(1);
#pragma unroll
                for (int h = 0; h < 2; ++h)
#pragma unroll
                    for (int j = 0; j < 2; ++j)
                        acc[h][j] = __builtin_amdgcn_mfma_f32_16x16x32_bf16(
                            af[h][kq * 2 + s], b0[j], acc[h][j], 0, 0, 0);
                __builtin_amdgcn_s_setprio(0);
            }
            if (kq == 3) {
                // epilogue: sigmoid -> sG; gate col at slot ((col+1)&1023)^x8
#pragma unroll
                for (int j = 0; j < 2; ++j) {
                    int col = g * 128 + wc * 32 + j * 16 + l15;
                    int sl = (col + 1) & 1023;
#pragma unroll
                    for (int h = 0; h < 2; ++h) {
                        float g0 = 1.f / (1.f + __expf(-(acc[h][j][0] + bs[j])));
                        float g1 = 1.f / (1.f + __expf(-(acc[h][j][1] + bs[j])));
                        float g2 = 1.f / (1.f + __expf(-(acc[h][j][2] + bs[j])));
                        float g3 = 1.f / (1.f + __expf(-(acc[h][j][3] + bs[j])));
                        unsigned p0 = pkbf(g0, g1), p1 = pkbf(g2, g3);
                        sG[eb[h][0] + (sl ^ ex[h][0])] = (ushortT)p0;
                        sG[eb[h][1] + (sl ^ ex[h][1])] = (ushortT)(p0 >> 16);
                        sG[eb[h][2] + (sl ^ ex[h][2])] = (ushortT)p1;
                        sG[eb[h][3] + (sl ^ ex[h][3])] = (ushortT)(p1 >> 16);
                    }
                }
            }
            WAITL0(); HWBAR(); CFENCE(); SB();
            if (!L || kq < 2) stage_p1(g * 4 + kq + 2, buf);
        }
    };
    for (int g = 0; g < 7; ++g) p1_group(g, RunTag{});
    p1_group(7, LastTag{});
    // P1's final lgkm+barrier synced sG for all waves; sS free; vmcnt==0.

    // ---- P3 z-phases 0,1 staged EARLY (T14): latency rides under all of P2 ----
    CFENCE();
    stage_p3(0, 0);
    stage_p3(1, 1);

    // ---- P2: tree; 8 rows per wave; conflict-free vector reads (R3 layout) ----
    {
        const int r0 = wave * 8;
        for (int rr = 0; rr < 8; ++rr) {
            const int row = r0 + rr;
            const int rowb = row << 10;
            const int x8 = swz8(row);
            float P = 1.f;
#pragma unroll
            for (int d = 0; d < 6; ++d) {
                int slot = (1 << d) + (lane >> (6 - d));   // gate (1<<d)-1 + ...
                float g = bf2f(sG[rowb + (slot ^ x8)]);
                int bit = (lane >> (5 - d)) & 1;
                P *= bit ? (1.f - g) : g;
            }
            // level 6: gate 63+lane (u16)
            float g6 = bf2f(sG[rowb + ((64 + lane) ^ x8)]);
            float va = P * g6, vb = P - va;
            // level 7: gates 127+2L,128+2L (b32, coalesced)
            unsigned w7 = *(const unsigned*)(sG + rowb + ((128 + 2 * lane) ^ x8));
            float v4[4];
            {
                float ga = bf2f((ushortT)w7), gbv = bf2f((ushortT)(w7 >> 16));
                v4[0] = va * ga;  v4[1] = va - v4[0];
                v4[2] = vb * gbv; v4[3] = vb - v4[2];
            }
            // level 8: gates 255+4L..+4 (b64, coalesced)
            const unsigned* p8 = (const unsigned*)(sG + rowb + ((256 + 4 * lane) ^ x8));
            unsigned w8a = p8[0], w8b = p8[1];
            float v8[8];
            {
                float h0 = bf2f((ushortT)w8a), h1 = bf2f((ushortT)(w8a >> 16));
                float h2 = bf2f((ushortT)w8b), h3 = bf2f((ushortT)(w8b >> 16));
                v8[0] = v4[0] * h0; v8[1] = v4[0] - v8[0];
                v8[2] = v4[1] * h1; v8[3] = v4[1] - v8[2];
                v8[4] = v4[2] * h2; v8[5] = v4[2] - v8[4];
                v8[6] = v4[3] * h3; v8[7] = v4[3] - v8[6];
            }
            // level 9: gates 511+8L..+8 (b128, lane->consecutive 16B slots)
            bf16x8 g9 = *(const bf16x8*)(sG + rowb + ((512 + 8 * lane) ^ x8));
            float v16[16];
#pragma unroll
            for (int t = 0; t < 8; ++t) {
                float g = bf2f((ushortT)g9[t]);
                float a = v8[t] * g;
                v16[2 * t] = a;
                v16[2 * t + 1] = v8[t] - a;
            }
            // leaves: block 2L -> slot L^x; block 2L+1 -> 64+(L^x); both b128
            // writes stride-16B conflict-free; row-local => in-place safe.
            union { unsigned u[4]; bf16x8 v; } q0, q1;
#pragma unroll
            for (int t = 0; t < 4; ++t) q0.u[t] = pkbf(v16[2 * t], v16[2 * t + 1]);
#pragma unroll
            for (int t = 0; t < 4; ++t) q1.u[t] = pkbf(v16[8 + 2 * t], v16[9 + 2 * t]);
            int a0u = rowb + ((lane << 3) ^ x8);
            *(bf16x8*)(sG + a0u) = q0.v;
            *(bf16x8*)(sG + a0u + 512) = q1.v;
        }
    }
    // P2 -> P3: leaf writes visible to all waves; no vmem drain (z in flight)
    WAITL0(); HWBAR(); CFENCE(); SB();

    // ---- P3: out = leaf @ z^T; 16 phases x 2 substeps; counted pipe ----
    {
        int rowbA[2], xA[2];
#pragma unroll
        for (int h = 0; h < 2; ++h) {
            int rowA = wr * 32 + h * 16 + l15;
            rowbA[h] = rowA << 10;
            xA[h] = swz8(rowA);
        }
        f32x4 acc[2][2] = {};
        auto p3_phase = [&](int zp, bool doStage) {
            HWBAR(); CFENCE(); SB();
            const int buf = zp & 1;
#pragma unroll
            for (int s = 0; s < 2; ++s) {
                int t32 = zp * 2 + s;
                bf16x8 a0[2], b0[2];
#pragma unroll
                for (int h = 0; h < 2; ++h) {
                    int b = 4 * t32 + quad;  // leaf block index
                    int us = ((b & 1) << 9) + ((((b >> 1) << 3)) ^ xA[h]);
                    a0[h] = *(const bf16x8*)(sG + rowbA[h] + us);
                }
#pragma unroll
                for (int j = 0; j < 2; ++j)
                    b0[j] = *(const bf16x8*)(&sS[buf][s * 4096 +
                                                      (wc * 32 + j * 16 + l15) * 32 +
                                                      quad * 8]);
                __builtin_amdgcn_s_setprio(1);
#pragma unroll
                for (int h = 0; h < 2; ++h)
#pragma unroll
                    for (int j = 0; j < 2; ++j)
                        acc[h][j] = __builtin_amdgcn_mfma_f32_16x16x32_bf16(
                            a0[h], b0[j], acc[h][j], 0, 0, 0);
                __builtin_amdgcn_s_setprio(0);
            }
            WAITL0(); HWBAR(); CFENCE(); SB();
            if (doStage) stage_p3(zp + 2, zp & 1);
        };
        for (int zp = 0; zp < 14; ++zp) { WAITV(2); p3_phase(zp, true); }
        WAITV(2); p3_phase(14, false);
        WAITV(0); p3_phase(15, false);

        const int gm = bm + wr * 32 + quad * 4;
#pragma unroll
        for (int h = 0; h < 2; ++h)
#pragma unroll
            for (int j = 0; j < 2; ++j) {
                int gn = wc * 32 + j * 16 + l15;
#pragma unroll
                for (int r = 0; r < 4; ++r)
                    out[(size_t)(gm + h * 16 + r) * OUTF + gn] = acc[h][j][r];
            }
    }
}

// ---------------- launch ----------------
extern "C" void kernel_launch(void* const* d_in, const int* in_sizes, int n_in,
                              void* d_out, int out_size, void* d_ws, size_t ws_size,
                              hipStream_t stream) {
    const float* x  = (const float*)d_in[0];   // 16384 x 256
    const float* gw = (const float*)d_in[1];   // 256 x 1023
    const float* gb = (const float*)d_in[2];   // 1023
    const float* z  = (const float*)d_in[3];   // 128 x 1024
    float* out = (float*)d_out;                // 16384 x 128

    char* ws = (char*)d_ws;
    ushortT* gwT = (ushortT*)(ws + 0);       // 524,288 B
    ushortT* zh  = (ushortT*)(ws + 524288);  // 262,144 B
    float*   gbp = (float*)  (ws + 786432);  //   4,096 B (total < 1 MB)

    k_prep<<<129, 256, 0, stream>>>(gw, gb, z, gwT, gbp, zh);
    k_mega<<<256, 512, 0, stream>>>(x, gwT, gbp, zh, out);
}

// Round 8
// 117.973 us; speedup vs baseline: 1.0423x; 1.0423x over previous
//
#include <hip/hip_runtime.h>
#include <hip/hip_bf16.h>

// Problem constants
#define BATCH  16384
#define GATES  1023
#define NPAD   1024
#define OUTF   128

typedef unsigned short ushortT;
typedef short bf16x8 __attribute__((ext_vector_type(8)));
typedef float f32x4 __attribute__((ext_vector_type(4)));

__device__ inline float bf2f(ushortT u) {
    union { unsigned int i; float f; } v;
    v.i = ((unsigned int)u) << 16;
    return v.f;
}
__device__ inline ushortT f2bf(float f) {
    union { float f; unsigned int i; } v;
    v.f = f;
    unsigned int x = v.i;
    unsigned int r = (x + 0x7FFFu + ((x >> 16) & 1u)) >> 16;  // RNE
    return (ushortT)r;
}
// packed f32 pair -> bf16 pair (RNE); compiler lowers to v_cvt_pk_bf16_f32.
__device__ inline unsigned pkbf(float lo, float hi) {
    __hip_bfloat162 h = __float22bfloat162_rn(float2{lo, hi});
    union { __hip_bfloat162 h; unsigned u; } c;
    c.h = h;
    return c.u;
}
// Row-XOR on ushort-index bits 3..5. Spreads multi-row accesses (P1 epilogue
// quads, P3 A-reads). Row-uniform P2 is conflict-free by layout: gate g at
// slot (g+1)^x8 -> deep-tree reads are stride-16B vector reads; slot x8
// (image of 0) is the hole absorbing pad col 1023. [R3-measured: 262K]
__device__ inline int swz8(int row) { return (((row ^ (row >> 3)) & 7) << 3); }

// async global->LDS, 16B/lane; lds base wave-uniform, HW writes base + lane*16.
__device__ inline void gl2lds16(const void* gptr, void* ldsptr) {
    __builtin_amdgcn_global_load_lds(
        (const __attribute__((address_space(1))) void*)gptr,
        (__attribute__((address_space(3))) void*)ldsptr, 16, 0, 0);
}

// Counted-vmcnt raw-barrier discipline (T4 / m201 pattern)
#define WAITV(N) asm volatile("s_waitcnt vmcnt(" #N ")" ::: "memory")
#define WAITL0() asm volatile("s_waitcnt lgkmcnt(0)" ::: "memory")
#define CFENCE() asm volatile("" ::: "memory")
#define HWBAR()  __builtin_amdgcn_s_barrier()
#define SB()     __builtin_amdgcn_sched_barrier(0)

struct RunTag  { static constexpr bool last = false; };
struct LastTag { static constexpr bool last = true;  };

// ---------------- prep: gwT (tiled transpose+pad), zh, gbp ----------------
__global__ __launch_bounds__(256) void k_prep(const float* __restrict__ gw,
                                              const float* __restrict__ gb,
                                              const float* __restrict__ z,
                                              ushortT* __restrict__ gwT,
                                              float* __restrict__ gbp,
                                              ushortT* __restrict__ zh) {
    const int b = blockIdx.x, t = threadIdx.x;
    if (b < 64) {
        __shared__ ushortT tile[64][65];  // pad 65: transposed reads conflict-free
        const int k0 = (b >> 4) * 64, n0 = (b & 15) * 64;
        const int tr = t >> 6, tc = t & 63;
#pragma unroll
        for (int p = 0; p < 16; ++p) {
            int k = p * 4 + tr;
            int n = n0 + tc;
            float v = (n < GATES) ? gw[(size_t)(k0 + k) * GATES + n] : 0.f;
            tile[k][tc] = f2bf(v);
        }
        __syncthreads();
#pragma unroll
        for (int p = 0; p < 2; ++p) {
            int nn = (t >> 3) + p * 32;
            int ks = (t & 7) * 8;
            ushortT o[8];
#pragma unroll
            for (int u = 0; u < 8; ++u) o[u] = tile[ks + u][nn];
            *(bf16x8*)(gwT + (size_t)(n0 + nn) * 256 + k0 + ks) = *(bf16x8*)o;
        }
    } else if (b < 128) {
        int i = (b - 64) * 256 + t;
        const float4* p = (const float4*)z + (size_t)i * 2;
        float4 a = p[0], c = p[1];
        union { unsigned u[4]; bf16x8 v; } o;
        o.u[0] = pkbf(a.x, a.y); o.u[1] = pkbf(a.z, a.w);
        o.u[2] = pkbf(c.x, c.y); o.u[3] = pkbf(c.z, c.w);
        *(bf16x8*)(zh + (size_t)i * 8) = o.v;
    } else {
#pragma unroll
        for (int u = 0; u < 4; ++u) {
            int id = t * 4 + u;
            gbp[id] = (id < GATES) ? gb[id] : 0.f;
        }
    }
}

// ---------------- mega: one block = 64 rows, 1024 threads (16 waves) --------
// OCCUPANCY round: identical structure/traffic to R7, but 16 waves per block
// -> 4 waves/SIMD (vs 2 everywhere before). LDS 160 KB, 1 block/CU, 256
// blocks. Wave grid 4M x 4N: 16 rows x 32 cols per wave, af[8], acc[2].
// Staging: 1 gl2lds per wave per 16KB phase; steady WAITV(1), peeled tails.
// x-loads + ALL bias loads hoisted before prologue stages -> no mid-loop
// vmem, exact vmcnt counting.
__global__ __launch_bounds__(1024, 4) void k_mega(const float* __restrict__ x,
                                                  const ushortT* __restrict__ gwT,
                                                  const float* __restrict__ gbp,
                                                  const ushortT* __restrict__ zh,
                                                  float* __restrict__ out) {
    __shared__ __align__(16) ushortT sG[64 * 1024];  // 128 KB
    __shared__ __align__(16) ushortT sS[2][8192];    // 2 x 16 KB

    const int tid = threadIdx.x;
    const int wave = tid >> 6, lane = tid & 63;
    const int quad = lane >> 4, l15 = lane & 15;
    const int wr = wave >> 2, wc = wave & 3;   // 4M x 4N; wave tile 16 x 32
    const int bm = blockIdx.x * 64;
    const int srow = lane >> 2;                // staging row within 16-row group
    const int scol = (lane & 3) * 8;           // staging elem col within 32
    const int kcS = wave >> 3, eS = wave & 7;  // this wave's staging slot (16 waves = 16 x 1KB)

    // per-lane staging source bases
    const ushortT* gS = gwT + (size_t)srow * 256 + scol;
    const ushortT* zS = zh + (size_t)srow * 1024 + scol;

    // phase p (0..31): gates n0=(p>>2)*128, k-quarter k0=(p&3)*64; 16 KB, 1 issue/wave
    auto stage_p1 = [&](int p, int buf) {
        int n0 = (p >> 2) << 7, k0 = (p & 3) << 6;
        gl2lds16(gS + (size_t)(n0 + eS * 16) * 256 + k0 + kcS * 32,
                 (void*)&sS[buf][kcS * 4096 + eS * 512]);
    };
    // z-phase zp (0..15): all 128 z-rows, k = zp*64 .. +64; 16 KB, 1 issue/wave
    auto stage_p3 = [&](int zp, int buf) {
        gl2lds16(zS + (size_t)(eS * 16) * 1024 + zp * 64 + kcS * 32,
                 (void*)&sS[buf][kcS * 4096 + eS * 512]);
    };

    // ---- preload A: x rows (f32) -> bf16 frags; af[c]: row wr*16+l15, k=c*32+quad*8
    bf16x8 af[8];
    {
        const float* xr = x + (size_t)(bm + wr * 16 + l15) * 256;
#pragma unroll
        for (int c = 0; c < 8; ++c) {
            const float4* p = (const float4*)(xr + c * 32 + quad * 8);
            float4 a = p[0], b = p[1];
            union { unsigned u[4]; bf16x8 v; } o;
            o.u[0] = pkbf(a.x, a.y); o.u[1] = pkbf(a.z, a.w);
            o.u[2] = pkbf(b.x, b.y); o.u[3] = pkbf(b.z, b.w);
            af[c] = o.v;
        }
    }
    // ---- bias preload for all 8 groups (before stages: keeps vmcnt exact)
    float bsA[8][2];
#pragma unroll
    for (int g = 0; g < 8; ++g) {
        bsA[g][0] = gbp[g * 128 + wc * 32 + l15];
        bsA[g][1] = gbp[g * 128 + wc * 32 + 16 + l15];
    }

    // epilogue row constants (C/D: col=l15, row=quad*4+reg)
    int eb[4], ex[4];
#pragma unroll
    for (int r = 0; r < 4; ++r) {
        int row = wr * 16 + quad * 4 + r;
        eb[r] = row << 10;
        ex[r] = swz8(row);
    }

    // ---- P1 prologue: stage phases 0,1 (newest vmem ops after the fence)
    CFENCE();
    stage_p1(0, 0);
    stage_p1(1, 1);

    // ---- P1: 8 groups (128 gates) x 4 k-quarter phases; counted pipe ----
    auto p1_group = [&](int g, auto tag) {
        constexpr bool L = decltype(tag)::last;
        f32x4 acc[2] = {};
#pragma unroll
        for (int kq = 0; kq < 4; ++kq) {
            if (L && kq == 3) { WAITV(0); } else { WAITV(1); }
            HWBAR(); CFENCE(); SB();
            const int buf = kq & 1;
#pragma unroll
            for (int s = 0; s < 2; ++s) {
                bf16x8 b0[2];
#pragma unroll
                for (int j = 0; j < 2; ++j)
                    b0[j] = *(const bf16x8*)(&sS[buf][s * 4096 +
                                                      (wc * 32 + j * 16 + l15) * 32 +
                                                      quad * 8]);
                __builtin_amdgcn_s_setprio(1);
#pragma unroll
                for (int j = 0; j < 2; ++j)
                    acc[j] = __builtin_amdgcn_mfma_f32_16x16x32_bf16(
                        af[kq * 2 + s], b0[j], acc[j], 0, 0, 0);
                __builtin_amdgcn_s_setprio(0);
            }
            if (kq == 3) {
                // epilogue: sigmoid -> sG; gate col at slot ((col+1)&1023)^x8
#pragma unroll
                for (int j = 0; j < 2; ++j) {
                    int col = g * 128 + wc * 32 + j * 16 + l15;
                    int sl = (col + 1) & 1023;
                    float g0 = 1.f / (1.f + __expf(-(acc[j][0] + bsA[g][j])));
                    float g1 = 1.f / (1.f + __expf(-(acc[j][1] + bsA[g][j])));
                    float g2 = 1.f / (1.f + __expf(-(acc[j][2] + bsA[g][j])));
                    float g3 = 1.f / (1.f + __expf(-(acc[j][3] + bsA[g][j])));
                    unsigned p0 = pkbf(g0, g1), p1 = pkbf(g2, g3);
                    sG[eb[0] + (sl ^ ex[0])] = (ushortT)p0;
                    sG[eb[1] + (sl ^ ex[1])] = (ushortT)(p0 >> 16);
                    sG[eb[2] + (sl ^ ex[2])] = (ushortT)p1;
                    sG[eb[3] + (sl ^ ex[3])] = (ushortT)(p1 >> 16);
                }
            }
            WAITL0(); HWBAR(); CFENCE(); SB();
            if (!L || kq < 2) stage_p1(g * 4 + kq + 2, buf);
        }
    };
    for (int g = 0; g < 7; ++g) p1_group(g, RunTag{});
    p1_group(7, LastTag{});
    // P1's final lgkm+barrier synced sG for all waves; sS free; vmcnt==0.

    // ---- P3 z-phases 0,1 staged EARLY (T14): latency rides under all of P2 ----
    CFENCE();
    stage_p3(0, 0);
    stage_p3(1, 1);

    // ---- P2: tree; 4 rows per wave; conflict-free vector reads (R3 layout) ----
    {
        const int r0 = wave * 4;
        for (int rr = 0; rr < 4; ++rr) {
            const int row = r0 + rr;
            const int rowb = row << 10;
            const int x8 = swz8(row);
            float P = 1.f;
#pragma unroll
            for (int d = 0; d < 6; ++d) {
                int slot = (1 << d) + (lane >> (6 - d));   // gate (1<<d)-1 + ...
                float g = bf2f(sG[rowb + (slot ^ x8)]);
                int bit = (lane >> (5 - d)) & 1;
                P *= bit ? (1.f - g) : g;
            }
            // level 6: gate 63+lane (u16)
            float g6 = bf2f(sG[rowb + ((64 + lane) ^ x8)]);
            float va = P * g6, vb = P - va;
            // level 7: gates 127+2L,128+2L (b32, coalesced)
            unsigned w7 = *(const unsigned*)(sG + rowb + ((128 + 2 * lane) ^ x8));
            float v4[4];
            {
                float ga = bf2f((ushortT)w7), gbv = bf2f((ushortT)(w7 >> 16));
                v4[0] = va * ga;  v4[1] = va - v4[0];
                v4[2] = vb * gbv; v4[3] = vb - v4[2];
            }
            // level 8: gates 255+4L..+4 (b64, coalesced)
            const unsigned* p8 = (const unsigned*)(sG + rowb + ((256 + 4 * lane) ^ x8));
            unsigned w8a = p8[0], w8b = p8[1];
            float v8[8];
            {
                float h0 = bf2f((ushortT)w8a), h1 = bf2f((ushortT)(w8a >> 16));
                float h2 = bf2f((ushortT)w8b), h3 = bf2f((ushortT)(w8b >> 16));
                v8[0] = v4[0] * h0; v8[1] = v4[0] - v8[0];
                v8[2] = v4[1] * h1; v8[3] = v4[1] - v8[2];
                v8[4] = v4[2] * h2; v8[5] = v4[2] - v8[4];
                v8[6] = v4[3] * h3; v8[7] = v4[3] - v8[6];
            }
            // level 9: gates 511+8L..+8 (b128, lane->consecutive 16B slots)
            bf16x8 g9 = *(const bf16x8*)(sG + rowb + ((512 + 8 * lane) ^ x8));
            float v16[16];
#pragma unroll
            for (int t = 0; t < 8; ++t) {
                float g = bf2f((ushortT)g9[t]);
                float a = v8[t] * g;
                v16[2 * t] = a;
                v16[2 * t + 1] = v8[t] - a;
            }
            // leaves: block 2L -> slot L^x; block 2L+1 -> 64+(L^x); both b128
            // writes stride-16B conflict-free; row-local => in-place safe.
            union { unsigned u[4]; bf16x8 v; } q0, q1;
#pragma unroll
            for (int t = 0; t < 4; ++t) q0.u[t] = pkbf(v16[2 * t], v16[2 * t + 1]);
#pragma unroll
            for (int t = 0; t < 4; ++t) q1.u[t] = pkbf(v16[8 + 2 * t], v16[9 + 2 * t]);
            int a0u = rowb + ((lane << 3) ^ x8);
            *(bf16x8*)(sG + a0u) = q0.v;
            *(bf16x8*)(sG + a0u + 512) = q1.v;
        }
    }
    // P2 -> P3: leaf writes visible to all waves; no vmem drain (z in flight)
    WAITL0(); HWBAR(); CFENCE(); SB();

    // ---- P3: out = leaf @ z^T; 16 phases x 2 substeps; counted pipe ----
    {
        const int rowA = wr * 16 + l15;
        const int rowbA = rowA << 10;
        const int xA8 = swz8(rowA);
        f32x4 acc[2] = {};
        auto p3_phase = [&](int zp, bool doStage) {
            HWBAR(); CFENCE(); SB();
            const int buf = zp & 1;
#pragma unroll
            for (int s = 0; s < 2; ++s) {
                int t32 = zp * 2 + s;
                int b = 4 * t32 + quad;  // leaf block index
                int us = ((b & 1) << 9) + ((((b >> 1) << 3)) ^ xA8);
                bf16x8 a0 = *(const bf16x8*)(sG + rowbA + us);
                bf16x8 b0[2];
#pragma unroll
                for (int j = 0; j < 2; ++j)
                    b0[j] = *(const bf16x8*)(&sS[buf][s * 4096 +
                                                      (wc * 32 + j * 16 + l15) * 32 +
                                                      quad * 8]);
                __builtin_amdgcn_s_setprio(1);
#pragma unroll
                for (int j = 0; j < 2; ++j)
                    acc[j] = __builtin_amdgcn_mfma_f32_16x16x32_bf16(
                        a0, b0[j], acc[j], 0, 0, 0);
                __builtin_amdgcn_s_setprio(0);
            }
            WAITL0(); HWBAR(); CFENCE(); SB();
            if (doStage) stage_p3(zp + 2, zp & 1);
        };
        for (int zp = 0; zp < 14; ++zp) { WAITV(1); p3_phase(zp, true); }
        WAITV(1); p3_phase(14, false);
        WAITV(0); p3_phase(15, false);

        const int gm = bm + wr * 16 + quad * 4;
#pragma unroll
        for (int j = 0; j < 2; ++j) {
            int gn = wc * 32 + j * 16 + l15;
#pragma unroll
            for (int r = 0; r < 4; ++r)
                out[(size_t)(gm + r) * OUTF + gn] = acc[j][r];
        }
    }
}

// ---------------- launch ----------------
extern "C" void kernel_launch(void* const* d_in, const int* in_sizes, int n_in,
                              void* d_out, int out_size, void* d_ws, size_t ws_size,
                              hipStream_t stream) {
    const float* x  = (const float*)d_in[0];   // 16384 x 256
    const float* gw = (const float*)d_in[1];   // 256 x 1023
    const float* gb = (const float*)d_in[2];   // 1023
    const float* z  = (const float*)d_in[3];   // 128 x 1024
    float* out = (float*)d_out;                // 16384 x 128

    char* ws = (char*)d_ws;
    ushortT* gwT = (ushortT*)(ws + 0);       // 524,288 B
    ushortT* zh  = (ushortT*)(ws + 524288);  // 262,144 B
    float*   gbp = (float*)  (ws + 786432);  //   4,096 B (total < 1 MB)

    k_prep<<<129, 256, 0, stream>>>(gw, gb, z, gwT, gbp, zh);
    k_mega<<<256, 1024, 0, stream>>>(x, gwT, gbp, zh, out);
}